// Round 9
// baseline (106.243 us; speedup 1.0000x reference)
//
#include <hip/hip_runtime.h>

#define C_S 384
#define C_H 128
#define NROWS 512

typedef float f4 __attribute__((ext_vector_type(4)));

// Kernel A: byte-identical to round 8.
// 1024 blocks (1 row each); 4 waves x 4 lane-groups(16); single barrier;
// LN stats redundant per-wave; LN affine in-register.
__global__ __launch_bounds__(256, 4) void proj_ln_out(
    const float* __restrict__ s1, const float* __restrict__ s2,
    const float* __restrict__ W1, const float* __restrict__ b1,
    const float* __restrict__ W2, const float* __restrict__ b2,
    const float* __restrict__ gamma, const float* __restrict__ beta,
    const float* __restrict__ Wout, const float* __restrict__ bout,
    float* __restrict__ u, float* __restrict__ v)
{
    const int bid = blockIdx.x;
    const bool isA = bid < NROWS;
    const int r = isA ? bid : bid - NROWS;
    const float* __restrict__ src  = isA ? s1 : s2;
    const float* __restrict__ W    = isA ? W1 : W2;
    const float* __restrict__ bias = isA ? b1 : b2;
    float* __restrict__ dst = isA ? u : v;
    const int wout_off = isA ? 0 : C_H;

    const int tid  = threadIdx.x;
    const int wv   = tid >> 6;    // wave 0..3
    const int lane = tid & 63;
    const int g    = lane >> 4;   // lane-group 0..3
    const int j    = lane & 15;   // lane-in-group

    __shared__ __align__(16) float ylds[C_H];   // y + bias for this row

    // s k-slice in registers: k = 24j..24j+23 (6 x float4)
    f4 sreg[6];
    {
        const float* p = src + r * C_S + j * 24;
        #pragma unroll
        for (int q = 0; q < 6; ++q)
            sreg[q] = *reinterpret_cast<const f4*>(p + 4 * q);
    }

    // ---- GEMM 1: y[h] = W[h] . s + b[h]  (K = 384) ----
    #pragma unroll 2
    for (int i = 0; i < 8; ++i) {
        const int h = wv * 32 + i * 4 + g;
        const float* wp = W + h * C_S + j * 24;
        f4 wr[6];
        #pragma unroll
        for (int q = 0; q < 6; ++q)
            wr[q] = *reinterpret_cast<const f4*>(wp + 4 * q);
        f4 a = wr[0] * sreg[0];
        #pragma unroll
        for (int q = 1; q < 6; ++q) a += wr[q] * sreg[q];
        float acc = (a.x + a.y) + (a.z + a.w);
        #pragma unroll
        for (int off = 1; off < 16; off <<= 1)
            acc += __shfl_xor(acc, off);
        if (j == 0) ylds[h] = acc + bias[h];
    }
    __syncthreads();

    // ---- LN stats: each wave reduces redundantly (all lanes busy) ----
    const float y0 = ylds[lane];
    const float y1 = ylds[lane + 64];
    float s = y0 + y1, q = y0 * y0 + y1 * y1;
    #pragma unroll
    for (int off = 1; off < 64; off <<= 1) {
        s += __shfl_xor(s, off);
        q += __shfl_xor(q, off);
    }
    const float mu  = s * (1.0f / C_H);
    const float var = q * (1.0f / C_H) - mu * mu;
    const float rs  = rsqrtf(var + 1e-5f);

    // lane j's GEMM2 fragment: LN of channels [8j, 8j+8) applied in-register
    f4 l0 = *reinterpret_cast<const f4*>(&ylds[j * 8]);
    f4 l1 = *reinterpret_cast<const f4*>(&ylds[j * 8 + 4]);
    const f4 g0 = *reinterpret_cast<const f4*>(gamma + j * 8);
    const f4 g1 = *reinterpret_cast<const f4*>(gamma + j * 8 + 4);
    const f4 be0 = *reinterpret_cast<const f4*>(beta + j * 8);
    const f4 be1 = *reinterpret_cast<const f4*>(beta + j * 8 + 4);
    #pragma unroll
    for (int c = 0; c < 4; ++c) {
        l0[c] = (l0[c] - mu) * rs * g0[c] + be0[c];
        l1[c] = (l1[c] - mu) * rs * g1[c] + be1[c];
    }

    // ---- GEMM 2: z[zc] = Wout[zc, off:off+128] . ln  (K = 128) ----
    const float invD = (float)(1.0 / (0.001 + 262144.0));
    #pragma unroll 2
    for (int i = 0; i < 8; ++i) {
        const int zc = wv * 32 + i * 4 + g;
        const float* wp = Wout + zc * (2 * C_H) + wout_off + j * 8;
        const f4 w0 = *reinterpret_cast<const f4*>(wp);
        const f4 w1 = *reinterpret_cast<const f4*>(wp + 4);
        f4 a = w0 * l0 + w1 * l1;
        float acc = (a.x + a.y) + (a.z + a.w);
        #pragma unroll
        for (int off = 1; off < 16; off <<= 1)
            acc += __shfl_xor(acc, off);
        if (j == 0)
            dst[r * C_H + zc] = acc * invD + (isA ? bout[zc] : 0.f);
    }
}

// Kernel B MEASUREMENT: body identical to round 8, but 4 internal store
// passes. asm-volatile opacity on the per-rep value defeats store-sinking
// (round 7's rep loop was elided) while keeping stored bits identical.
// T9 - T8 = 3*B_pass; dispatch ~4*B tops rocprof table -> true hbm_gbps.
#define NTHREADS (2048 * 256)
#define BREPS 4
__global__ __launch_bounds__(256) void bcast_add(
    const float* __restrict__ u, const float* __restrict__ v,
    float* __restrict__ out)
{
    const size_t tid = (size_t)blockIdx.x * 256 + threadIdx.x;
    const f4* __restrict__ uq = reinterpret_cast<const f4*>(u);
    f4* __restrict__ oq = reinterpret_cast<f4*>(out);
    f4 v4 = reinterpret_cast<const f4*>(v)[tid & 16383];
    const int zq = (int)(tid & 31);
    #pragma unroll 1
    for (int rep = 0; rep < BREPS; ++rep) {
        // opaque no-op: v4 "may have changed" -> stores can't be sunk/elided
        float t0 = v4.x;
        asm volatile("" : "+v"(t0));
        v4.x = t0;
        #pragma unroll
        for (int k = 0; k < 16; ++k) {
            const size_t i = tid + (size_t)k * NTHREADS;
            const size_t un = i >> 14;              // n index 0..511
            oq[i] = uq[(un << 5) | zq] + v4;
        }
    }
}

extern "C" void kernel_launch(void* const* d_in, const int* in_sizes, int n_in,
                              void* d_out, int out_size, void* d_ws, size_t ws_size,
                              hipStream_t stream) {
    const float* s1    = (const float*)d_in[0];
    const float* s2    = (const float*)d_in[1];
    const float* W1    = (const float*)d_in[2];
    const float* b1    = (const float*)d_in[3];
    const float* W2    = (const float*)d_in[4];
    const float* b2    = (const float*)d_in[5];
    const float* gamma = (const float*)d_in[6];
    const float* beta  = (const float*)d_in[7];
    const float* Wout  = (const float*)d_in[8];
    const float* bout  = (const float*)d_in[9];

    float* u = (float*)d_ws;                 // 512*128 fp32
    float* v = u + NROWS * C_H;              // 512*128 fp32

    proj_ln_out<<<2 * NROWS, 256, 0, stream>>>(s1, s2, W1, b1, W2, b2,
                                               gamma, beta, Wout, bout, u, v);
    bcast_add<<<2048, 256, 0, stream>>>(u, v, (float*)d_out);
}